// Round 3
// baseline (292.254 us; speedup 1.0000x reference)
//
#include <hip/hip_runtime.h>
#include <cstdint>

#define B_ 4
#define S_ 4096
#define D_ 512
#define M_ (B_*S_)   // 16384 rows

typedef _Float16 f16;
typedef _Float16 f16x8 __attribute__((ext_vector_type(8)));
typedef _Float16 f16x2 __attribute__((ext_vector_type(2)));
typedef float    f32x4 __attribute__((ext_vector_type(4)));

typedef __attribute__((address_space(1))) void* as1p;
typedef __attribute__((address_space(3))) void* as3p;

__device__ __forceinline__ void gl2lds16(const void* g, void* l) {
    __builtin_amdgcn_global_load_lds((as1p)g, (as3p)l, 16, 0, 0);
}

union f16pack { f16x8 v8; f16x2 v2[4]; };

__device__ __forceinline__ float agent_load_f(const float* p) {
    return __hip_atomic_load(p, __ATOMIC_RELAXED, __HIP_MEMORY_SCOPE_AGENT);
}
__device__ __forceinline__ int agent_load_i(const int* p) {
    return __hip_atomic_load(p, __ATOMIC_RELAXED, __HIP_MEMORY_SCOPE_AGENT);
}

// ---------------- weight prep: v<64: Wv transpose tile; v in 64..127: Wl f16 cast ----------------
__device__ __forceinline__ void weight_job(int v, int t, char* SMEM,
    const float* __restrict__ Wv, const float* __restrict__ Wl,
    f16* __restrict__ WvT, f16* __restrict__ WlH)
{
    const int z = v >> 6, tile_id = v & 63;
    if (z == 1) {    // Wl cast (row-major f16)
        const size_t base = (size_t)tile_id*4096 + (size_t)t*16;
        const float4* s4 = (const float4*)(Wl + base);
        float4 a0 = s4[0], a1 = s4[1], a2 = s4[2], a3 = s4[3];
        f16x8 o0, o1;
        o0[0]=(f16)a0.x; o0[1]=(f16)a0.y; o0[2]=(f16)a0.z; o0[3]=(f16)a0.w;
        o0[4]=(f16)a1.x; o0[5]=(f16)a1.y; o0[6]=(f16)a1.z; o0[7]=(f16)a1.w;
        o1[0]=(f16)a2.x; o1[1]=(f16)a2.y; o1[2]=(f16)a2.z; o1[3]=(f16)a2.w;
        o1[4]=(f16)a3.x; o1[5]=(f16)a3.y; o1[6]=(f16)a3.z; o1[7]=(f16)a3.w;
        *(f16x8*)(WlH + base)     = o0;
        *(f16x8*)(WlH + base + 8) = o1;
        return;
    }
    // Wv transpose tile -> WvT[j][i] = Wv[i][j]
    float (*tile)[68] = (float(*)[68])SMEM;
    const int bx = tile_id & 7, by = tile_id >> 3;
    const int i0 = bx*64, j0 = by*64;
    const int r = t >> 2, cpart = (t & 3)*16;
    {
        const float4* s4 = (const float4*)(Wv + (size_t)(i0 + r)*512 + j0 + cpart);
        float4 a0 = s4[0], a1 = s4[1], a2 = s4[2], a3 = s4[3];
        *(float4*)&tile[r][cpart]    = a0;
        *(float4*)&tile[r][cpart+4]  = a1;
        *(float4*)&tile[r][cpart+8]  = a2;
        *(float4*)&tile[r][cpart+12] = a3;
    }
    __syncthreads();
    const int c = t >> 2, rpart = (t & 3)*16;
    f16x8 o0, o1;
    #pragma unroll
    for (int q = 0; q < 8; q++) o0[q] = (f16)tile[rpart + q][c];
    #pragma unroll
    for (int q = 0; q < 8; q++) o1[q] = (f16)tile[rpart + 8 + q][c];
    *(f16x8*)(WvT + (size_t)(j0 + c)*512 + i0 + rpart)     = o0;
    *(f16x8*)(WvT + (size_t)(j0 + c)*512 + i0 + rpart + 8) = o1;
}

// ---------------- xs cast + per-block column partials (j = 0..255, 64 rows each) ----------------
// ends right after the partial store; caller syncs/fences.
__device__ __forceinline__ void xs_job64(int j, int t, char* SMEM,
    const float* __restrict__ xs, f16* __restrict__ xs_h,
    float* __restrict__ xpart)
{
    float* red = (float*)SMEM;   // [4][512]
    const int w = t >> 6, l = t & 63;
    const int col = l * 8;
    float acc[8] = {0,0,0,0,0,0,0,0};
    for (int c = 0; c < 16; c++) {
        int row = j*64 + c*4 + w;
        const float4* p = (const float4*)(xs + (size_t)row*512 + col);
        float4 a = p[0], b = p[1];
        f16x8 o;
        o[0]=(f16)a.x; o[1]=(f16)a.y; o[2]=(f16)a.z; o[3]=(f16)a.w;
        o[4]=(f16)b.x; o[5]=(f16)b.y; o[6]=(f16)b.z; o[7]=(f16)b.w;
        *(f16x8*)(xs_h + (size_t)row*512 + col) = o;
        acc[0]+=a.x; acc[1]+=a.y; acc[2]+=a.z; acc[3]+=a.w;
        acc[4]+=b.x; acc[5]+=b.y; acc[6]+=b.z; acc[7]+=b.w;
    }
    #pragma unroll
    for (int q = 0; q < 8; q++) red[w*512 + col + q] = acc[q];
    __syncthreads();
    #pragma unroll
    for (int k = 0; k < 2; k++) {
        int c = t + k*256;
        xpart[(size_t)j*512 + c] = red[c] + red[512+c] + red[1024+c] + red[1536+c];
    }
}

// ---------------- chained matvec partial (helper rank q handles d in [q*128, q*128+128)):
//   g[d] = rowW[d,:].v + sbias*rbias[d];  outc += sum_d g[d]*cdot[d];
//   outv[j] += sum_d colW[d][j]*g[d]   (4-way atomicAdd partials) ----------------
__device__ __forceinline__ void chain_partial(int q, int t, char* SMEM,
    const float* __restrict__ rowW, const float* __restrict__ colW,
    const float* __restrict__ rbias, const float* __restrict__ cdot,
    float sbias, const float* __restrict__ vsrc,
    float* __restrict__ outv, float* __restrict__ outc)
{
    float* vv = (float*)SMEM;        // 512
    float* gg = vv + 512;            // 128
    for (int i = t; i < 512; i += 256)
        vv[i] = agent_load_f(vsrc + i);
    __syncthreads();
    const int w = t >> 6, l = t & 63, p = l & 15, g4 = l >> 4;
    float vs[32];
    #pragma unroll
    for (int c = 0; c < 32; c++) vs[c] = vv[p*32 + c];
    const int d0 = q*128;
    float cacc = 0.f;
    for (int it = 0; it < 8; it++) {
        const int r = d0 + w*32 + it*4 + g4;
        const float4* wr = (const float4*)(rowW + (size_t)r*512 + p*32);
        float acc = 0.f;
        #pragma unroll
        for (int u4 = 0; u4 < 8; u4++) {
            float4 a = wr[u4];
            acc += a.x*vs[u4*4] + a.y*vs[u4*4+1] + a.z*vs[u4*4+2] + a.w*vs[u4*4+3];
        }
        acc += __shfl_xor(acc, 1);
        acc += __shfl_xor(acc, 2);
        acc += __shfl_xor(acc, 4);
        acc += __shfl_xor(acc, 8);
        if (p == 0) {
            float gv = acc + sbias * rbias[r];
            gg[r - d0] = gv;
            cacc += gv * cdot[r];
        }
    }
    if (p == 0) atomicAdd(outc, cacc);
    __syncthreads();
    float a0 = 0.f, a1 = 0.f;
    const int c0 = 2*t;
    #pragma unroll 4
    for (int d = 0; d < 128; d++) {
        const float gd = gg[d];
        const float2 wv2 = *(const float2*)(colW + (size_t)(d0 + d)*512 + c0);
        a0 += gd * wv2.x;
        a1 += gd * wv2.y;
    }
    atomicAdd(&outv[c0], a0);
    atomicAdd(&outv[c0 + 1], a1);
}

// ---------------- k1: weight prep (0..127) || xs cast+partials (128..383) + h-chain tail ----------------
__global__ __launch_bounds__(256, 2) void k1_kernel(
    const float* __restrict__ xs,
    const float* __restrict__ Wv, const float* __restrict__ Wl,
    const float* __restrict__ Wk, const float* __restrict__ Wq,
    const float* __restrict__ bk, const float* __restrict__ bq,
    f16* __restrict__ xs_h, float* __restrict__ xpart, float* __restrict__ xsSum,
    f16* __restrict__ WvT, f16* __restrict__ WlH,
    float* __restrict__ hG, float* __restrict__ c1G,
    int* __restrict__ tickA, int* __restrict__ tickB)
{
    __shared__ __attribute__((aligned(16))) char SMEM[17408];
    __shared__ int oldv;
    const int blk = blockIdx.x, t = threadIdx.x;
    if (blk < 128) { weight_job(blk, t, SMEM, Wv, Wl, WvT, WlH); return; }
    const int j = blk - 128, b = j >> 6;
    xs_job64(j, t, SMEM, xs, xs_h, xpart);
    __syncthreads();          // drain partial stores (per-wave vmcnt0)
    __threadfence();
    if (t == 0) oldv = atomicAdd(&tickA[b], 1);
    __syncthreads();
    const int old = oldv;
    if (old < 60) return;
    const int q = old - 60;   // helper rank 0..3
    if (t == 0) {
        while (agent_load_i(&tickA[b]) < 64) __builtin_amdgcn_s_sleep(8);
    }
    __syncthreads();
    __threadfence();
    // reduce 64 partials -> xsSum slice [q*128, q*128+128)
    float* red2 = (float*)SMEM;
    {
        const int colq = q*128 + (t & 127);
        const int half = t >> 7;
        float s = 0.f;
        #pragma unroll 8
        for (int p = half*32; p < half*32 + 32; p++)
            s += xpart[(size_t)(b*64 + p)*512 + colq];
        red2[t] = s;
        __syncthreads();
        if (t < 128) xsSum[b*512 + q*128 + t] = red2[t] + red2[t + 128];
    }
    __syncthreads();
    __threadfence();
    if (t == 0) {
        atomicAdd(&tickB[b], 1);
        while (agent_load_i(&tickB[b]) < 4) __builtin_amdgcn_s_sleep(2);
    }
    __syncthreads();
    __threadfence();
    // g1 = Wk@xsSum_b + 4096*bk ; hG[b] += Wq^T g1 (slice) ; c1[b] += bq.g1 (slice)
    chain_partial(q, t, SMEM, Wk, Wq, bk, bq, 4096.0f,
                  xsSum + b*512, hG + (size_t)b*512, c1G + b);
}

// ---------------- Wvl GEMM job (v = 0..63): WvlH = WlH @ WvT^T, + bvl ----------------
__device__ __forceinline__ void wvl_job(int v, int t, char* SMEM,
    const f16* __restrict__ WlH, const f16* __restrict__ WvT,
    const float* __restrict__ Wl, const float* __restrict__ bv,
    f16* __restrict__ WvlH, float* __restrict__ bvlG)
{
    f16* lA = (f16*)SMEM;          // 4KB
    f16* lB = lA + 64*32;          // 4KB
    const int bx = v & 7, by = v >> 3;
    const int i0 = bx*64, j0 = by*64;
    const int lane = t & 63, wid = t >> 6;
    const int wm = (wid & 1)*32, wn = (wid >> 1)*32;
    const int srow = t >> 2, skb = (t & 3) << 4;
    const long aoff = (long)(i0 + srow)*1024 + skb;
    const long boff = (long)(j0 + srow)*1024 + skb;
    const unsigned wbase = (unsigned)wid << 10;
    f32x4 acc[2][2] = {};
    const int ael = (wm + (lane & 15))*32 + ((lane >> 4) << 3);
    const int bel = (wn + (lane & 15))*32 + ((lane >> 4) << 3);
    for (int k0 = 0; k0 < 512; k0 += 32) {
        __syncthreads();
        gl2lds16((const char*)WlH + aoff + k0*2, (char*)lA + wbase);
        gl2lds16((const char*)WvT + boff + k0*2, (char*)lB + wbase);
        __syncthreads();
        f16x8 af[2], bf[2];
        af[0] = *(const f16x8*)(lA + ael);
        af[1] = *(const f16x8*)(lA + ael + 512);
        bf[0] = *(const f16x8*)(lB + bel);
        bf[1] = *(const f16x8*)(lB + bel + 512);
        #pragma unroll
        for (int i = 0; i < 2; i++)
            #pragma unroll
            for (int j = 0; j < 2; j++)
                acc[i][j] = __builtin_amdgcn_mfma_f32_16x16x32_f16(af[i], bf[j], acc[i][j], 0, 0, 0);
    }
    const int rb = wm + ((lane >> 4) << 2);
    const int cb = wn + (lane & 15);
    #pragma unroll
    for (int i = 0; i < 2; i++)
        #pragma unroll
        for (int j = 0; j < 2; j++)
            #pragma unroll
            for (int r = 0; r < 4; r++)
                WvlH[(size_t)(i0 + rb + i*16 + r)*512 + j0 + cb + j*16] = (f16)acc[i][j][r];
    if (by == 0) {
        int r = t >> 2, part = t & 3;
        const float4* wr = (const float4*)(Wl + (size_t)(i0+r)*512 + part*128);
        const float4* bp = (const float4*)(bv + part*128);
        float s = 0.f;
        #pragma unroll 8
        for (int q = 0; q < 32; q++) {
            float4 wv4 = wr[q], b4 = bp[q];
            s += wv4.x*b4.x + wv4.y*b4.y + wv4.z*b4.z + wv4.w*b4.w;
        }
        s += __shfl_xor(s, 1);
        s += __shfl_xor(s, 2);
        if (part == 0) bvlG[i0 + r] = s;
    }
}

// ---------------- z pass (z = 0..511, 32 rows): iv = 1/(4096+(xs.h+c1)/512); partials out ----------------
__device__ __forceinline__ void z_job(int z, int t, char* SMEM,
    const f16* __restrict__ xs_h, const float* __restrict__ hG,
    const float* __restrict__ c1G, float* __restrict__ zpart, float* __restrict__ s0part)
{
    float* hs    = (float*)SMEM;      // 512
    float* yred  = hs + 512;          // [4][512]
    float* s0red = yred + 2048;       // [4]
    const int b = z >> 7, w = t >> 6, l = t & 63;
    hs[t] = hG[(size_t)b*512 + t]; hs[t+256] = hG[(size_t)b*512 + t + 256];
    __syncthreads();
    const float c1 = c1G[b];
    float hx[8];
    #pragma unroll
    for (int q = 0; q < 8; q++) hx[q] = hs[l*8+q];
    float yacc[8] = {0,0,0,0,0,0,0,0};
    float s0acc = 0.f;
    for (int it = 0; it < 8; it++) {
        int row = z*32 + w*8 + it;
        f16x8 v = *(const f16x8*)(xs_h + (size_t)row*512 + l*8);
        float xf[8];
        #pragma unroll
        for (int q = 0; q < 8; q++) xf[q] = (float)v[q];
        float d = 0.f;
        #pragma unroll
        for (int q = 0; q < 8; q++) d += xf[q]*hx[q];
        #pragma unroll
        for (int m = 1; m < 64; m <<= 1) d += __shfl_xor(d, m);
        float zz = 4096.0f + (d + c1)*(1.0f/512.0f);
        float iv = 1.0f/zz;
        s0acc += iv;
        #pragma unroll
        for (int q = 0; q < 8; q++) yacc[q] += iv*xf[q];
    }
    #pragma unroll
    for (int q = 0; q < 8; q++) yred[w*512 + l*8+q] = yacc[q];
    if (l == 0) s0red[w] = s0acc;
    __syncthreads();
    #pragma unroll
    for (int k = 0; k < 2; k++) {
        int c = t + k*256;
        zpart[(size_t)z*512 + c] = yred[c]+yred[512+c]+yred[1024+c]+yred[1536+c];
    }
    if (t == 0) s0part[z] = s0red[0]+s0red[1]+s0red[2]+s0red[3];
}

// ---------------- k3: Wvl GEMM (0..63) || z pass (64..575) + u-chain tail ----------------
__global__ __launch_bounds__(256, 2) void k3_kernel(
    const f16* __restrict__ xs_h,
    const float* __restrict__ hG, const float* __restrict__ c1G,
    float* __restrict__ zpart, float* __restrict__ s0part,
    float* __restrict__ yG, float* __restrict__ S0G,
    const f16* __restrict__ WlH, const f16* __restrict__ WvT,
    const float* __restrict__ Wl, const float* __restrict__ bv,
    f16* __restrict__ WvlH, float* __restrict__ bvlG,
    const float* __restrict__ Wk, const float* __restrict__ Wq,
    const float* __restrict__ bk, const float* __restrict__ bq,
    float* __restrict__ uG, f16* __restrict__ uH, float* __restrict__ c2G,
    int* __restrict__ tickZ, int* __restrict__ tickY, int* __restrict__ tickU)
{
    __shared__ __attribute__((aligned(16))) char SMEM[10304];
    __shared__ int oldv, oldv2;
    const int blk = blockIdx.x, t = threadIdx.x;
    if (blk < 64) { wvl_job(blk, t, SMEM, WlH, WvT, Wl, bv, WvlH, bvlG); return; }
    const int z = blk - 64, b = z >> 7;
    z_job(z, t, SMEM, xs_h, hG, c1G, zpart, s0part);
    __syncthreads();
    __threadfence();
    if (t == 0) oldv = atomicAdd(&tickZ[b], 1);
    __syncthreads();
    const int old = oldv;
    if (old < 124) return;
    const int q = old - 124;  // helper rank 0..3
    if (t == 0) {
        while (agent_load_i(&tickZ[b]) < 128) __builtin_amdgcn_s_sleep(8);
    }
    __syncthreads();
    __threadfence();
    // reduce 128 partials -> yG slice [q*128, q*128+128)
    float* red2 = (float*)SMEM;
    {
        const int colq = q*128 + (t & 127);
        const int half = t >> 7;
        float s = 0.f;
        #pragma unroll 8
        for (int p = half*64; p < half*64 + 64; p++)
            s += zpart[(size_t)(b*128 + p)*512 + colq];
        red2[t] = s;
        __syncthreads();
        if (t < 128) yG[b*512 + q*128 + t] = red2[t] + red2[t + 128];
    }
    if (q == 0) {   // S0 reduction (helper 0 only; block-uniform branch)
        float s0 = (t < 128) ? s0part[b*128 + t] : 0.f;
        #pragma unroll
        for (int m = 1; m < 64; m <<= 1) s0 += __shfl_xor(s0, m);
        __syncthreads();
        if ((t & 63) == 0 && t < 128) red2[t >> 6] = s0;
        __syncthreads();
        if (t == 0)
            __hip_atomic_store(&S0G[b], red2[0] + red2[1],
                               __ATOMIC_RELAXED, __HIP_MEMORY_SCOPE_AGENT);
    }
    __syncthreads();
    __threadfence();
    if (t == 0) {
        atomicAdd(&tickY[b], 1);
        while (agent_load_i(&tickY[b]) < 4) __builtin_amdgcn_s_sleep(2);
    }
    __syncthreads();
    __threadfence();
    const float S0b = agent_load_f(&S0G[b]);
    // g2 = Wq@y_b + S0*bq ; uG[b] += Wk^T g2 (slice) ; c2[b] += bk.g2 (slice)
    chain_partial(q, t, SMEM, Wq, Wk, bq, bk, S0b,
                  yG + b*512, uG + (size_t)b*512, c2G + b);
    __threadfence();
    __syncthreads();
    if (t == 0) oldv2 = atomicAdd(&tickU[b], 1);
    __syncthreads();
    if (oldv2 == 3) {   // last helper finalizes f16 cast of u
        __threadfence();
        for (int i = t; i < 512; i += 256)
            uH[(size_t)b*512 + i] = (f16)agent_load_f(uG + (size_t)b*512 + i);
    }
}

// ---------------- vl_gemm: out = tanh(rs*(xs@Wvl^T + bvl) + bl), rs fused via v_dot2 ----------------
__global__ __launch_bounds__(256, 2) void vl_gemm(const f16* __restrict__ A,
    const f16* __restrict__ Bt, const float* __restrict__ bvlG,
    const float* __restrict__ blG, const f16* __restrict__ uH,
    const float* __restrict__ c2G, const float* __restrict__ S0G,
    float* __restrict__ out)
{
    constexpr int K = 512;
    __shared__ f16 lA[128*32];
    __shared__ f16 lB[128*32];
    __shared__ float rsbuf[128];
    const int t = threadIdx.x;
    const int m0 = blockIdx.x*128, n0 = blockIdx.y*128;
    const int lane = t & 63, wid = t >> 6;
    const int wm = (wid & 1) << 6, wn = (wid >> 1) << 6;
    const int srow = t >> 2, skb = (t & 3) << 4;
    const long aoff0 = (long)(m0 + srow)*(K*2) + skb;
    const long aoff1 = aoff0 + 64L*(K*2);
    const long boff0 = (long)(n0 + srow)*(K*2) + skb;
    const long boff1 = boff0 + 64L*(K*2);
    char* ldsA = (char*)lA;
    char* ldsB = (char*)lB;
    const unsigned wbase = (unsigned)wid << 10;
    const char* Ab = (const char*)A;
    const char* Bb = (const char*)Bt;

    const int bat = blockIdx.x >> 5;          // 32 m-tiles per batch
    const f16* u = uH + bat*512;
    const int ku = (lane >> 4) << 3;

    f32x4 acc[4][4] = {};
    float racc[4] = {0.f,0.f,0.f,0.f};
    const int ael = (wm + (lane & 15))*32 + ku;
    const int bel = (wn + (lane & 15))*32 + ku;

    for (int k0 = 0; k0 < K; k0 += 32) {
        __syncthreads();
        const long kb = (long)k0*2;
        gl2lds16(Ab + aoff0 + kb, ldsA + wbase);
        gl2lds16(Ab + aoff1 + kb, ldsA + 4096 + wbase);
        gl2lds16(Bb + boff0 + kb, ldsB + wbase);
        gl2lds16(Bb + boff1 + kb, ldsB + 4096 + wbase);
        __syncthreads();
        f16x8 af[4], bf[4];
        #pragma unroll
        for (int i = 0; i < 4; i++) af[i] = *(const f16x8*)(lA + ael + i*512);
        #pragma unroll
        for (int j = 0; j < 4; j++) bf[j] = *(const f16x8*)(lB + bel + j*512);
        f16pack up; up.v8 = *(const f16x8*)(u + k0 + ku);
        #pragma unroll
        for (int i = 0; i < 4; i++) {
            f16pack ap; ap.v8 = af[i];
            #pragma unroll
            for (int q = 0; q < 4; q++)
                racc[i] = __builtin_amdgcn_fdot2(ap.v2[q], up.v2[q], racc[i], false);
        }
        #pragma unroll
        for (int i = 0; i < 4; i++)
            #pragma unroll
            for (int j = 0; j < 4; j++)
                acc[i][j] = __builtin_amdgcn_mfma_f32_16x16x32_f16(af[i], bf[j], acc[i][j], 0, 0, 0);
    }

    #pragma unroll
    for (int i = 0; i < 4; i++) {
        racc[i] += __shfl_xor(racc[i], 16);
        racc[i] += __shfl_xor(racc[i], 32);
    }
    const float S0 = S0G[bat], c2 = c2G[bat];
    if (wid < 2 && lane < 16) {
        #pragma unroll
        for (int i = 0; i < 4; i++)
            rsbuf[wm + i*16 + lane] = S0 + (racc[i] + c2)*(1.0f/512.0f);
    }
    __syncthreads();

    const int crb = m0 + wm + ((lane >> 4) << 2);
    const int ccb = n0 + wn + (lane & 15);
    const int lrb = wm + ((lane >> 4) << 2);
    #pragma unroll
    for (int i = 0; i < 4; i++) {
        float rsv[4];
        #pragma unroll
        for (int r = 0; r < 4; r++) rsv[r] = rsbuf[lrb + i*16 + r];
        #pragma unroll
        for (int j = 0; j < 4; j++) {
            int c = ccb + j*16;
            float bb = bvlG[c], bo = blG[c];
            #pragma unroll
            for (int r = 0; r < 4; r++) {
                float yv = rsv[r]*(acc[i][j][r] + bb) + bo;
                float e2 = __expf(2.0f*yv);
                out[(size_t)(crb + i*16 + r)*512 + c] = 1.0f - 2.0f/(e2 + 1.0f);
            }
        }
    }
}

extern "C" void kernel_launch(void* const* d_in, const int* in_sizes, int n_in,
                              void* d_out, int out_size, void* d_ws, size_t ws_size,
                              hipStream_t stream)
{
    const float* xs = (const float*)d_in[0];
    const float* Wk = (const float*)d_in[1];
    const float* bk = (const float*)d_in[2];
    const float* Wq = (const float*)d_in[3];
    const float* bq = (const float*)d_in[4];
    const float* Wv = (const float*)d_in[5];
    const float* bv = (const float*)d_in[6];
    const float* Wl = (const float*)d_in[7];
    const float* bl = (const float*)d_in[8];
    float* out = (float*)d_out;

    char* w = (char*)d_ws;
    f16*   xs_h = (f16*)w;   w += (size_t)M_*D_*2;   // 16.8 MB
    f16*   WvlH = (f16*)w;   w += (size_t)D_*D_*2;
    f16*   WlH  = (f16*)w;   w += (size_t)D_*D_*2;
    f16*   WvT  = (f16*)w;   w += (size_t)D_*D_*2;
    f16*   uH   = (f16*)w;   w += (size_t)B_*D_*2;
    float* bvlG = (float*)w; w += (size_t)D_*4;
    float* xpart= (float*)w; w += (size_t)256*512*4;   // 512 KB
    float* zpart= (float*)w; w += (size_t)512*512*4;   // 1 MB
    float* s0part=(float*)w; w += (size_t)512*4;
    float* xsSum= (float*)w; w += (size_t)B_*D_*4;
    float* yG   = (float*)w; w += (size_t)B_*D_*4;
    float* S0G  = (float*)w; w += B_*4;
    // ---- zero region (one async memset; atomic targets + tickets) ----
    char* z0 = w;
    float* hG   = (float*)w; w += (size_t)B_*D_*4;
    float* uG   = (float*)w; w += (size_t)B_*D_*4;
    float* c1G  = (float*)w; w += B_*4;
    float* c2G  = (float*)w; w += B_*4;
    int*   tickA= (int*)w;   w += B_*4;
    int*   tickB= (int*)w;   w += B_*4;
    int*   tickZ= (int*)w;   w += B_*4;
    int*   tickY= (int*)w;   w += B_*4;
    int*   tickU= (int*)w;   w += B_*4;
    const size_t zbytes = (size_t)(w - z0);
    if ((size_t)(w - (char*)d_ws) > ws_size) return;  // fail loudly

    hipMemsetAsync(z0, 0, zbytes, stream);

    k1_kernel<<<384, 256, 0, stream>>>(xs, Wv, Wl, Wk, Wq, bk, bq,
        xs_h, xpart, xsSum, WvT, WlH, hG, c1G, tickA, tickB);

    k3_kernel<<<576, 256, 0, stream>>>(xs_h, hG, c1G, zpart, s0part, yG, S0G,
        WlH, WvT, Wl, bv, WvlH, bvlG, Wk, Wq, bk, bq,
        uG, uH, c2G, tickZ, tickY, tickU);

    vl_gemm<<<dim3(128,4), 256, 0, stream>>>(xs_h, WvlH, bvlG, bl, uH, c2G, S0G, out);
}

// Round 4
// 189.913 us; speedup vs baseline: 1.5389x; 1.5389x over previous
//
#include <hip/hip_runtime.h>
#include <cstdint>

#define B_ 4
#define S_ 4096
#define D_ 512
#define M_ (B_*S_)   // 16384 rows

typedef _Float16 f16;
typedef _Float16 f16x8 __attribute__((ext_vector_type(8)));
typedef _Float16 f16x2 __attribute__((ext_vector_type(2)));
typedef float    f32x4 __attribute__((ext_vector_type(4)));

typedef __attribute__((address_space(1))) void* as1p;
typedef __attribute__((address_space(3))) void* as3p;

__device__ __forceinline__ void gl2lds16(const void* g, void* l) {
    __builtin_amdgcn_global_load_lds((as1p)g, (as3p)l, 16, 0, 0);
}

union f16pack { f16x8 v8; f16x2 v2[4]; };

// Agent-scope (device-coherent) point accesses: per-access sc1, NO cache-wide fence.
__device__ __forceinline__ float agent_load_f(const float* p) {
    return __hip_atomic_load(p, __ATOMIC_RELAXED, __HIP_MEMORY_SCOPE_AGENT);
}
__device__ __forceinline__ int agent_load_i(const int* p) {
    return __hip_atomic_load(p, __ATOMIC_RELAXED, __HIP_MEMORY_SCOPE_AGENT);
}
__device__ __forceinline__ void agent_store_f(float* p, float v) {
    __hip_atomic_store(p, v, __ATOMIC_RELAXED, __HIP_MEMORY_SCOPE_AGENT);
}

// ---------------- weight prep: v<64: Wv transpose tile; v in 64..127: Wl f16 cast ----------------
__device__ __forceinline__ void weight_job(int v, int t, char* SMEM,
    const float* __restrict__ Wv, const float* __restrict__ Wl,
    f16* __restrict__ WvT, f16* __restrict__ WlH)
{
    const int z = v >> 6, tile_id = v & 63;
    if (z == 1) {    // Wl cast (row-major f16)
        const size_t base = (size_t)tile_id*4096 + (size_t)t*16;
        const float4* s4 = (const float4*)(Wl + base);
        float4 a0 = s4[0], a1 = s4[1], a2 = s4[2], a3 = s4[3];
        f16x8 o0, o1;
        o0[0]=(f16)a0.x; o0[1]=(f16)a0.y; o0[2]=(f16)a0.z; o0[3]=(f16)a0.w;
        o0[4]=(f16)a1.x; o0[5]=(f16)a1.y; o0[6]=(f16)a1.z; o0[7]=(f16)a1.w;
        o1[0]=(f16)a2.x; o1[1]=(f16)a2.y; o1[2]=(f16)a2.z; o1[3]=(f16)a2.w;
        o1[4]=(f16)a3.x; o1[5]=(f16)a3.y; o1[6]=(f16)a3.z; o1[7]=(f16)a3.w;
        *(f16x8*)(WlH + base)     = o0;
        *(f16x8*)(WlH + base + 8) = o1;
        return;
    }
    // Wv transpose tile -> WvT[j][i] = Wv[i][j]
    float (*tile)[68] = (float(*)[68])SMEM;
    const int bx = tile_id & 7, by = tile_id >> 3;
    const int i0 = bx*64, j0 = by*64;
    const int r = t >> 2, cpart = (t & 3)*16;
    {
        const float4* s4 = (const float4*)(Wv + (size_t)(i0 + r)*512 + j0 + cpart);
        float4 a0 = s4[0], a1 = s4[1], a2 = s4[2], a3 = s4[3];
        *(float4*)&tile[r][cpart]    = a0;
        *(float4*)&tile[r][cpart+4]  = a1;
        *(float4*)&tile[r][cpart+8]  = a2;
        *(float4*)&tile[r][cpart+12] = a3;
    }
    __syncthreads();
    const int c = t >> 2, rpart = (t & 3)*16;
    f16x8 o0, o1;
    #pragma unroll
    for (int q = 0; q < 8; q++) o0[q] = (f16)tile[rpart + q][c];
    #pragma unroll
    for (int q = 0; q < 8; q++) o1[q] = (f16)tile[rpart + 8 + q][c];
    *(f16x8*)(WvT + (size_t)(j0 + c)*512 + i0 + rpart)     = o0;
    *(f16x8*)(WvT + (size_t)(j0 + c)*512 + i0 + rpart + 8) = o1;
}

// ---------------- xs cast + per-block column partials (j = 0..255, 64 rows each) ----------------
__device__ __forceinline__ void xs_job64(int j, int t, char* SMEM,
    const float* __restrict__ xs, f16* __restrict__ xs_h,
    float* __restrict__ xpart)
{
    float* red = (float*)SMEM;   // [4][512]
    const int w = t >> 6, l = t & 63;
    const int col = l * 8;
    float acc[8] = {0,0,0,0,0,0,0,0};
    for (int c = 0; c < 16; c++) {
        int row = j*64 + c*4 + w;
        const float4* p = (const float4*)(xs + (size_t)row*512 + col);
        float4 a = p[0], b = p[1];
        f16x8 o;
        o[0]=(f16)a.x; o[1]=(f16)a.y; o[2]=(f16)a.z; o[3]=(f16)a.w;
        o[4]=(f16)b.x; o[5]=(f16)b.y; o[6]=(f16)b.z; o[7]=(f16)b.w;
        *(f16x8*)(xs_h + (size_t)row*512 + col) = o;
        acc[0]+=a.x; acc[1]+=a.y; acc[2]+=a.z; acc[3]+=a.w;
        acc[4]+=b.x; acc[5]+=b.y; acc[6]+=b.z; acc[7]+=b.w;
    }
    #pragma unroll
    for (int q = 0; q < 8; q++) red[w*512 + col + q] = acc[q];
    __syncthreads();
    #pragma unroll
    for (int k = 0; k < 2; k++) {
        int c = t + k*256;
        agent_store_f(&xpart[(size_t)j*512 + c],
                      red[c] + red[512+c] + red[1024+c] + red[1536+c]);
    }
}

// ---------------- chained matvec partial (helper rank q handles d in [q*128, q*128+128)):
//   g[d] = rowW[d,:].v + sbias*rbias[d];  outc += sum_d g[d]*cdot[d];
//   outv[j] += sum_d colW[d][j]*g[d]   (4-way atomicAdd partials) ----------------
__device__ __forceinline__ void chain_partial(int q, int t, char* SMEM,
    const float* __restrict__ rowW, const float* __restrict__ colW,
    const float* __restrict__ rbias, const float* __restrict__ cdot,
    float sbias, const float* __restrict__ vsrc,
    float* __restrict__ outv, float* __restrict__ outc)
{
    float* vv = (float*)SMEM;        // 512
    float* gg = vv + 512;            // 128
    for (int i = t; i < 512; i += 256)
        vv[i] = agent_load_f(vsrc + i);
    __syncthreads();
    const int w = t >> 6, l = t & 63, p = l & 15, g4 = l >> 4;
    float vs[32];
    #pragma unroll
    for (int c = 0; c < 32; c++) vs[c] = vv[p*32 + c];
    const int d0 = q*128;
    float cacc = 0.f;
    for (int it = 0; it < 8; it++) {
        const int r = d0 + w*32 + it*4 + g4;
        const float4* wr = (const float4*)(rowW + (size_t)r*512 + p*32);
        float acc = 0.f;
        #pragma unroll
        for (int u4 = 0; u4 < 8; u4++) {
            float4 a = wr[u4];
            acc += a.x*vs[u4*4] + a.y*vs[u4*4+1] + a.z*vs[u4*4+2] + a.w*vs[u4*4+3];
        }
        acc += __shfl_xor(acc, 1);
        acc += __shfl_xor(acc, 2);
        acc += __shfl_xor(acc, 4);
        acc += __shfl_xor(acc, 8);
        if (p == 0) {
            float gv = acc + sbias * rbias[r];
            gg[r - d0] = gv;
            cacc += gv * cdot[r];
        }
    }
    if (p == 0) atomicAdd(outc, cacc);
    __syncthreads();
    float a0 = 0.f, a1 = 0.f;
    const int c0 = 2*t;
    #pragma unroll 4
    for (int d = 0; d < 128; d++) {
        const float gd = gg[d];
        const float2 wv2 = *(const float2*)(colW + (size_t)(d0 + d)*512 + c0);
        a0 += gd * wv2.x;
        a1 += gd * wv2.y;
    }
    atomicAdd(&outv[c0], a0);
    atomicAdd(&outv[c0 + 1], a1);
}

// ---------------- k1: weight prep (0..127) || xs cast+partials (128..383) + h-chain tail ----------------
__global__ __launch_bounds__(256, 2) void k1_kernel(
    const float* __restrict__ xs,
    const float* __restrict__ Wv, const float* __restrict__ Wl,
    const float* __restrict__ Wk, const float* __restrict__ Wq,
    const float* __restrict__ bk, const float* __restrict__ bq,
    f16* __restrict__ xs_h, float* __restrict__ xpart, float* __restrict__ xsSum,
    f16* __restrict__ WvT, f16* __restrict__ WlH,
    float* __restrict__ hG, float* __restrict__ c1G,
    int* __restrict__ tickA, int* __restrict__ tickB)
{
    __shared__ __attribute__((aligned(16))) char SMEM[17408];
    __shared__ int oldv;
    const int blk = blockIdx.x, t = threadIdx.x;
    if (blk < 128) { weight_job(blk, t, SMEM, Wv, Wl, WvT, WlH); return; }
    const int j = blk - 128, b = j >> 6;
    xs_job64(j, t, SMEM, xs, xs_h, xpart);
    __syncthreads();          // drains each thread's sc1 stores (vmcnt0 before barrier)
    if (t == 0) oldv = atomicAdd(&tickA[b], 1);
    __syncthreads();
    const int old = oldv;
    if (old < 60) return;
    const int q = old - 60;   // helper rank 0..3
    if (t == 0) {
        while (agent_load_i(&tickA[b]) < 64) __builtin_amdgcn_s_sleep(8);
    }
    __syncthreads();
    // reduce 64 partials -> xsSum slice [q*128, q*128+128)
    float* red2 = (float*)SMEM;
    {
        const int colq = q*128 + (t & 127);
        const int half = t >> 7;
        float s = 0.f;
        #pragma unroll 8
        for (int p = half*32; p < half*32 + 32; p++)
            s += agent_load_f(&xpart[(size_t)(b*64 + p)*512 + colq]);
        red2[t] = s;
        __syncthreads();
        if (t < 128) agent_store_f(&xsSum[b*512 + q*128 + t], red2[t] + red2[t + 128]);
    }
    __syncthreads();          // drain xsSum stores before signaling
    if (t == 0) {
        atomicAdd(&tickB[b], 1);
        while (agent_load_i(&tickB[b]) < 4) __builtin_amdgcn_s_sleep(2);
    }
    __syncthreads();
    // g1 = Wk@xsSum_b + 4096*bk ; hG[b] += Wq^T g1 (slice) ; c1[b] += bq.g1 (slice)
    chain_partial(q, t, SMEM, Wk, Wq, bk, bq, 4096.0f,
                  xsSum + b*512, hG + (size_t)b*512, c1G + b);
}

// ---------------- Wvl GEMM job (v = 0..63): WvlH = WlH @ WvT^T, + bvl ----------------
__device__ __forceinline__ void wvl_job(int v, int t, char* SMEM,
    const f16* __restrict__ WlH, const f16* __restrict__ WvT,
    const float* __restrict__ Wl, const float* __restrict__ bv,
    f16* __restrict__ WvlH, float* __restrict__ bvlG)
{
    f16* lA = (f16*)SMEM;          // 4KB
    f16* lB = lA + 64*32;          // 4KB
    const int bx = v & 7, by = v >> 3;
    const int i0 = bx*64, j0 = by*64;
    const int lane = t & 63, wid = t >> 6;
    const int wm = (wid & 1)*32, wn = (wid >> 1)*32;
    const int srow = t >> 2, skb = (t & 3) << 4;
    const long aoff = (long)(i0 + srow)*1024 + skb;
    const long boff = (long)(j0 + srow)*1024 + skb;
    const unsigned wbase = (unsigned)wid << 10;
    f32x4 acc[2][2] = {};
    const int ael = (wm + (lane & 15))*32 + ((lane >> 4) << 3);
    const int bel = (wn + (lane & 15))*32 + ((lane >> 4) << 3);
    for (int k0 = 0; k0 < 512; k0 += 32) {
        __syncthreads();
        gl2lds16((const char*)WlH + aoff + k0*2, (char*)lA + wbase);
        gl2lds16((const char*)WvT + boff + k0*2, (char*)lB + wbase);
        __syncthreads();
        f16x8 af[2], bf[2];
        af[0] = *(const f16x8*)(lA + ael);
        af[1] = *(const f16x8*)(lA + ael + 512);
        bf[0] = *(const f16x8*)(lB + bel);
        bf[1] = *(const f16x8*)(lB + bel + 512);
        #pragma unroll
        for (int i = 0; i < 2; i++)
            #pragma unroll
            for (int j = 0; j < 2; j++)
                acc[i][j] = __builtin_amdgcn_mfma_f32_16x16x32_f16(af[i], bf[j], acc[i][j], 0, 0, 0);
    }
    const int rb = wm + ((lane >> 4) << 2);
    const int cb = wn + (lane & 15);
    #pragma unroll
    for (int i = 0; i < 2; i++)
        #pragma unroll
        for (int j = 0; j < 2; j++)
            #pragma unroll
            for (int r = 0; r < 4; r++)
                WvlH[(size_t)(i0 + rb + i*16 + r)*512 + j0 + cb + j*16] = (f16)acc[i][j][r];
    if (by == 0) {
        int r = t >> 2, part = t & 3;
        const float4* wr = (const float4*)(Wl + (size_t)(i0+r)*512 + part*128);
        const float4* bp = (const float4*)(bv + part*128);
        float s = 0.f;
        #pragma unroll 8
        for (int q = 0; q < 32; q++) {
            float4 wv4 = wr[q], b4 = bp[q];
            s += wv4.x*b4.x + wv4.y*b4.y + wv4.z*b4.z + wv4.w*b4.w;
        }
        s += __shfl_xor(s, 1);
        s += __shfl_xor(s, 2);
        if (part == 0) bvlG[i0 + r] = s;
    }
}

// ---------------- z pass (z = 0..511, 32 rows): iv = 1/(4096+(xs.h+c1)/512); partials out ----------------
__device__ __forceinline__ void z_job(int z, int t, char* SMEM,
    const f16* __restrict__ xs_h, const float* __restrict__ hG,
    const float* __restrict__ c1G, float* __restrict__ zpart, float* __restrict__ s0part)
{
    float* hs    = (float*)SMEM;      // 512
    float* yred  = hs + 512;          // [4][512]
    float* s0red = yred + 2048;       // [4]
    const int b = z >> 7, w = t >> 6, l = t & 63;
    hs[t] = hG[(size_t)b*512 + t]; hs[t+256] = hG[(size_t)b*512 + t + 256];
    __syncthreads();
    const float c1 = c1G[b];
    float hx[8];
    #pragma unroll
    for (int q = 0; q < 8; q++) hx[q] = hs[l*8+q];
    float yacc[8] = {0,0,0,0,0,0,0,0};
    float s0acc = 0.f;
    for (int it = 0; it < 8; it++) {
        int row = z*32 + w*8 + it;
        f16x8 v = *(const f16x8*)(xs_h + (size_t)row*512 + l*8);
        float xf[8];
        #pragma unroll
        for (int q = 0; q < 8; q++) xf[q] = (float)v[q];
        float d = 0.f;
        #pragma unroll
        for (int q = 0; q < 8; q++) d += xf[q]*hx[q];
        #pragma unroll
        for (int m = 1; m < 64; m <<= 1) d += __shfl_xor(d, m);
        float zz = 4096.0f + (d + c1)*(1.0f/512.0f);
        float iv = 1.0f/zz;
        s0acc += iv;
        #pragma unroll
        for (int q = 0; q < 8; q++) yacc[q] += iv*xf[q];
    }
    #pragma unroll
    for (int q = 0; q < 8; q++) yred[w*512 + l*8+q] = yacc[q];
    if (l == 0) s0red[w] = s0acc;
    __syncthreads();
    #pragma unroll
    for (int k = 0; k < 2; k++) {
        int c = t + k*256;
        agent_store_f(&zpart[(size_t)z*512 + c],
                      yred[c]+yred[512+c]+yred[1024+c]+yred[1536+c]);
    }
    if (t == 0) agent_store_f(&s0part[z], s0red[0]+s0red[1]+s0red[2]+s0red[3]);
}

// ---------------- k3: Wvl GEMM (0..63) || z pass (64..575) + u-chain tail ----------------
__global__ __launch_bounds__(256, 2) void k3_kernel(
    const f16* __restrict__ xs_h,
    const float* __restrict__ hG, const float* __restrict__ c1G,
    float* __restrict__ zpart, float* __restrict__ s0part,
    float* __restrict__ yG, float* __restrict__ S0G,
    const f16* __restrict__ WlH, const f16* __restrict__ WvT,
    const float* __restrict__ Wl, const float* __restrict__ bv,
    f16* __restrict__ WvlH, float* __restrict__ bvlG,
    const float* __restrict__ Wk, const float* __restrict__ Wq,
    const float* __restrict__ bk, const float* __restrict__ bq,
    float* __restrict__ uG, f16* __restrict__ uH, float* __restrict__ c2G,
    int* __restrict__ tickZ, int* __restrict__ tickY, int* __restrict__ tickU)
{
    __shared__ __attribute__((aligned(16))) char SMEM[10304];
    __shared__ int oldv, oldv2;
    const int blk = blockIdx.x, t = threadIdx.x;
    if (blk < 64) { wvl_job(blk, t, SMEM, WlH, WvT, Wl, bv, WvlH, bvlG); return; }
    const int z = blk - 64, b = z >> 7;
    z_job(z, t, SMEM, xs_h, hG, c1G, zpart, s0part);
    __syncthreads();          // drains each thread's sc1 stores
    if (t == 0) oldv = atomicAdd(&tickZ[b], 1);
    __syncthreads();
    const int old = oldv;
    if (old < 124) return;
    const int q = old - 124;  // helper rank 0..3
    if (t == 0) {
        while (agent_load_i(&tickZ[b]) < 128) __builtin_amdgcn_s_sleep(8);
    }
    __syncthreads();
    // reduce 128 partials -> yG slice [q*128, q*128+128)
    float* red2 = (float*)SMEM;
    {
        const int colq = q*128 + (t & 127);
        const int half = t >> 7;
        float s = 0.f;
        #pragma unroll 8
        for (int p = half*64; p < half*64 + 64; p++)
            s += agent_load_f(&zpart[(size_t)(b*128 + p)*512 + colq]);
        red2[t] = s;
        __syncthreads();
        if (t < 128) agent_store_f(&yG[b*512 + q*128 + t], red2[t] + red2[t + 128]);
    }
    if (q == 0) {   // S0 reduction (helper 0 only; block-uniform branch)
        float s0 = (t < 128) ? agent_load_f(&s0part[b*128 + t]) : 0.f;
        #pragma unroll
        for (int m = 1; m < 64; m <<= 1) s0 += __shfl_xor(s0, m);
        __syncthreads();
        if ((t & 63) == 0 && t < 128) red2[t >> 6] = s0;
        __syncthreads();
        if (t == 0) agent_store_f(&S0G[b], red2[0] + red2[1]);
    }
    __syncthreads();          // drain yG/S0G stores before signaling
    if (t == 0) {
        atomicAdd(&tickY[b], 1);
        while (agent_load_i(&tickY[b]) < 4) __builtin_amdgcn_s_sleep(2);
    }
    __syncthreads();
    const float S0b = agent_load_f(&S0G[b]);
    // g2 = Wq@y_b + S0*bq ; uG[b] += Wk^T g2 (slice) ; c2[b] += bk.g2 (slice)
    chain_partial(q, t, SMEM, Wq, Wk, bq, bk, S0b,
                  yG + b*512, uG + (size_t)b*512, c2G + b);
    __syncthreads();          // drain uG/c2G atomics before signaling
    if (t == 0) oldv2 = atomicAdd(&tickU[b], 1);
    __syncthreads();
    if (oldv2 == 3) {   // last helper finalizes f16 cast of u
        for (int i = t; i < 512; i += 256)
            uH[(size_t)b*512 + i] = (f16)agent_load_f(uG + (size_t)b*512 + i);
    }
}

// ---------------- vl_gemm: out = tanh(rs*(xs@Wvl^T + bvl) + bl), rs fused via v_dot2 ----------------
__global__ __launch_bounds__(256, 2) void vl_gemm(const f16* __restrict__ A,
    const f16* __restrict__ Bt, const float* __restrict__ bvlG,
    const float* __restrict__ blG, const f16* __restrict__ uH,
    const float* __restrict__ c2G, const float* __restrict__ S0G,
    float* __restrict__ out)
{
    constexpr int K = 512;
    __shared__ f16 lA[128*32];
    __shared__ f16 lB[128*32];
    __shared__ float rsbuf[128];
    const int t = threadIdx.x;
    const int m0 = blockIdx.x*128, n0 = blockIdx.y*128;
    const int lane = t & 63, wid = t >> 6;
    const int wm = (wid & 1) << 6, wn = (wid >> 1) << 6;
    const int srow = t >> 2, skb = (t & 3) << 4;
    const long aoff0 = (long)(m0 + srow)*(K*2) + skb;
    const long aoff1 = aoff0 + 64L*(K*2);
    const long boff0 = (long)(n0 + srow)*(K*2) + skb;
    const long boff1 = boff0 + 64L*(K*2);
    char* ldsA = (char*)lA;
    char* ldsB = (char*)lB;
    const unsigned wbase = (unsigned)wid << 10;
    const char* Ab = (const char*)A;
    const char* Bb = (const char*)Bt;

    const int bat = blockIdx.x >> 5;          // 32 m-tiles per batch
    const f16* u = uH + bat*512;
    const int ku = (lane >> 4) << 3;

    f32x4 acc[4][4] = {};
    float racc[4] = {0.f,0.f,0.f,0.f};
    const int ael = (wm + (lane & 15))*32 + ku;
    const int bel = (wn + (lane & 15))*32 + ku;

    for (int k0 = 0; k0 < K; k0 += 32) {
        __syncthreads();
        const long kb = (long)k0*2;
        gl2lds16(Ab + aoff0 + kb, ldsA + wbase);
        gl2lds16(Ab + aoff1 + kb, ldsA + 4096 + wbase);
        gl2lds16(Bb + boff0 + kb, ldsB + wbase);
        gl2lds16(Bb + boff1 + kb, ldsB + 4096 + wbase);
        __syncthreads();
        f16x8 af[4], bf[4];
        #pragma unroll
        for (int i = 0; i < 4; i++) af[i] = *(const f16x8*)(lA + ael + i*512);
        #pragma unroll
        for (int j = 0; j < 4; j++) bf[j] = *(const f16x8*)(lB + bel + j*512);
        f16pack up; up.v8 = *(const f16x8*)(u + k0 + ku);
        #pragma unroll
        for (int i = 0; i < 4; i++) {
            f16pack ap; ap.v8 = af[i];
            #pragma unroll
            for (int q = 0; q < 4; q++)
                racc[i] = __builtin_amdgcn_fdot2(ap.v2[q], up.v2[q], racc[i], false);
        }
        #pragma unroll
        for (int i = 0; i < 4; i++)
            #pragma unroll
            for (int j = 0; j < 4; j++)
                acc[i][j] = __builtin_amdgcn_mfma_f32_16x16x32_f16(af[i], bf[j], acc[i][j], 0, 0, 0);
    }

    #pragma unroll
    for (int i = 0; i < 4; i++) {
        racc[i] += __shfl_xor(racc[i], 16);
        racc[i] += __shfl_xor(racc[i], 32);
    }
    const float S0 = S0G[bat], c2 = c2G[bat];
    if (wid < 2 && lane < 16) {
        #pragma unroll
        for (int i = 0; i < 4; i++)
            rsbuf[wm + i*16 + lane] = S0 + (racc[i] + c2)*(1.0f/512.0f);
    }
    __syncthreads();

    const int crb = m0 + wm + ((lane >> 4) << 2);
    const int ccb = n0 + wn + (lane & 15);
    const int lrb = wm + ((lane >> 4) << 2);
    #pragma unroll
    for (int i = 0; i < 4; i++) {
        float rsv[4];
        #pragma unroll
        for (int r = 0; r < 4; r++) rsv[r] = rsbuf[lrb + i*16 + r];
        #pragma unroll
        for (int j = 0; j < 4; j++) {
            int c = ccb + j*16;
            float bb = bvlG[c], bo = blG[c];
            #pragma unroll
            for (int r = 0; r < 4; r++) {
                float yv = rsv[r]*(acc[i][j][r] + bb) + bo;
                float e2 = __expf(2.0f*yv);
                out[(size_t)(crb + i*16 + r)*512 + c] = 1.0f - 2.0f/(e2 + 1.0f);
            }
        }
    }
}

extern "C" void kernel_launch(void* const* d_in, const int* in_sizes, int n_in,
                              void* d_out, int out_size, void* d_ws, size_t ws_size,
                              hipStream_t stream)
{
    const float* xs = (const float*)d_in[0];
    const float* Wk = (const float*)d_in[1];
    const float* bk = (const float*)d_in[2];
    const float* Wq = (const float*)d_in[3];
    const float* bq = (const float*)d_in[4];
    const float* Wv = (const float*)d_in[5];
    const float* bv = (const float*)d_in[6];
    const float* Wl = (const float*)d_in[7];
    const float* bl = (const float*)d_in[8];
    float* out = (float*)d_out;

    char* w = (char*)d_ws;
    f16*   xs_h = (f16*)w;   w += (size_t)M_*D_*2;   // 16.8 MB
    f16*   WvlH = (f16*)w;   w += (size_t)D_*D_*2;
    f16*   WlH  = (f16*)w;   w += (size_t)D_*D_*2;
    f16*   WvT  = (f16*)w;   w += (size_t)D_*D_*2;
    f16*   uH   = (f16*)w;   w += (size_t)B_*D_*2;
    float* bvlG = (float*)w; w += (size_t)D_*4;
    float* xpart= (float*)w; w += (size_t)256*512*4;   // 512 KB
    float* zpart= (float*)w; w += (size_t)512*512*4;   // 1 MB
    float* s0part=(float*)w; w += (size_t)512*4;
    float* xsSum= (float*)w; w += (size_t)B_*D_*4;
    float* yG   = (float*)w; w += (size_t)B_*D_*4;
    float* S0G  = (float*)w; w += B_*4;
    // ---- zero region (one async memset; atomic targets + tickets) ----
    char* z0 = w;
    float* hG   = (float*)w; w += (size_t)B_*D_*4;
    float* uG   = (float*)w; w += (size_t)B_*D_*4;
    float* c1G  = (float*)w; w += B_*4;
    float* c2G  = (float*)w; w += B_*4;
    int*   tickA= (int*)w;   w += B_*4;
    int*   tickB= (int*)w;   w += B_*4;
    int*   tickZ= (int*)w;   w += B_*4;
    int*   tickY= (int*)w;   w += B_*4;
    int*   tickU= (int*)w;   w += B_*4;
    const size_t zbytes = (size_t)(w - z0);
    if ((size_t)(w - (char*)d_ws) > ws_size) return;  // fail loudly

    hipMemsetAsync(z0, 0, zbytes, stream);

    k1_kernel<<<384, 256, 0, stream>>>(xs, Wv, Wl, Wk, Wq, bk, bq,
        xs_h, xpart, xsSum, WvT, WlH, hG, c1G, tickA, tickB);

    k3_kernel<<<576, 256, 0, stream>>>(xs_h, hG, c1G, zpart, s0part, yG, S0G,
        WlH, WvT, Wl, bv, WvlH, bvlG, Wk, Wq, bk, bq,
        uG, uH, c2G, tickZ, tickY, tickU);

    vl_gemm<<<dim3(128,4), 256, 0, stream>>>(xs_h, WvlH, bvlG, bl, uH, c2G, S0G, out);
}